// Round 6
// baseline (105.757 us; speedup 1.0000x reference)
//
#include <hip/hip_runtime.h>
#include <math.h>
#include <stdint.h>

#define NTRAIN 16384
#define DIM 64
#define ODIM 8
#define BATCH 8192

typedef float f32x16 __attribute__((ext_vector_type(16)));
typedef short short8 __attribute__((ext_vector_type(8)));
typedef unsigned short u16;

// float -> bf16 bits, RNE (no NaN in this data)
static __device__ __forceinline__ u16 f2bf(float f) {
  unsigned u = __builtin_bit_cast(unsigned, f);
  u += 0x7FFFu + ((u >> 16) & 1u);
  return (u16)(u >> 16);
}
static __device__ __forceinline__ float bf2f(u16 b) {
  unsigned u = ((unsigned)b) << 16;
  return __builtin_bit_cast(float, u);
}

static __device__ __forceinline__ f32x16 mfma32(short8 a, short8 b, f32x16 c) {
  return __builtin_amdgcn_mfma_f32_32x32x16_bf16(a, b, c, 0, 0, 0);
}
static __device__ __forceinline__ unsigned pkbf(float a, float b) {
  unsigned d;
  asm("v_cvt_pk_bf16_f32 %0, %1, %2" : "=v"(d) : "v"(a), "v"(b));
  return d;
}
static __device__ __forceinline__ float ex2(float x) {
  float r;
  asm("v_exp_f32 %0, %1" : "=v"(r) : "v"(x));
  return r;
}
static __device__ __forceinline__ void plswap(unsigned& a, unsigned& b) {
  asm("v_permlane32_swap_b32 %0, %1" : "+v"(a), "+v"(b));
}

// ---------------------------------------------------------------------------
// Fused prep: X hi/lo fragments, V fragments, norms, -beta*log2e.
// ---------------------------------------------------------------------------
__global__ __launch_bounds__(256) void k_prep(
    const float* __restrict__ batches, const float* __restrict__ xt,
    const float* __restrict__ yt, const float* __restrict__ beta,
    u16* __restrict__ xh, u16* __restrict__ xl, u16* __restrict__ yv,
    float* __restrict__ b2, float* __restrict__ x2, float* __restrict__ nb2) {
  int tid = blockIdx.x * 256 + threadIdx.x;

  if (tid < (NTRAIN / 32) * 4 * 64) {  // X fragments (2*x, hi/lo split)
    int frag = tid >> 6, lane = tid & 63;
    int ntile = frag >> 2, ks = frag & 3;
    int lr = lane & 31, hi = lane >> 5;
    const float* src = xt + (size_t)(ntile * 32 + lr) * DIM + ks * 16 + hi * 8;
    unsigned h[8], l[8];
#pragma unroll
    for (int j = 0; j < 8; ++j) {
      float v = 2.0f * src[j];
      u16 hb = f2bf(v);
      h[j] = hb;
      l[j] = f2bf(v - bf2f(hb));
    }
    uint4 uh, ul;
    uh.x = h[0] | (h[1] << 16); uh.y = h[2] | (h[3] << 16);
    uh.z = h[4] | (h[5] << 16); uh.w = h[6] | (h[7] << 16);
    ul.x = l[0] | (l[1] << 16); ul.y = l[2] | (l[3] << 16);
    ul.z = l[4] | (l[5] << 16); ul.w = l[6] | (l[7] << 16);
    ((uint4*)xh)[(size_t)frag * 64 + lane] = uh;
    ((uint4*)xl)[(size_t)frag * 64 + lane] = ul;
    return;
  }
  tid -= (NTRAIN / 32) * 4 * 64;

  if (tid < (NTRAIN / 16) * 64) {  // V = [1 | y | 0pad] fragments
    int frag = tid >> 6, lane = tid & 63;
    int col = lane & 31, hi = lane >> 5;
    int n = frag * 16 + hi * 8;
    unsigned e[8];
#pragma unroll
    for (int j = 0; j < 8; ++j) {
      float v = (col == 0) ? 1.0f : ((col < 9) ? yt[(size_t)(n + j) * ODIM + (col - 1)] : 0.0f);
      e[j] = f2bf(v);
    }
    uint4 u;
    u.x = e[0] | (e[1] << 16); u.y = e[2] | (e[3] << 16);
    u.z = e[4] | (e[5] << 16); u.w = e[6] | (e[7] << 16);
    ((uint4*)yv)[(size_t)frag * 64 + lane] = u;
    return;
  }
  tid -= (NTRAIN / 16) * 64;

  if (tid < BATCH + NTRAIN) {  // row norms
    const float* row;
    float* dst;
    if (tid < BATCH) { row = batches + (size_t)tid * DIM; dst = b2 + tid; }
    else { row = xt + (size_t)(tid - BATCH) * DIM; dst = x2 + (tid - BATCH); }
    const float4* r4 = (const float4*)row;
    float s0 = 0.f, s1 = 0.f, s2 = 0.f, s3 = 0.f;
#pragma unroll
    for (int q = 0; q < DIM / 4; ++q) {
      float4 v = r4[q];
      s0 = fmaf(v.x, v.x, s0); s1 = fmaf(v.y, v.y, s1);
      s2 = fmaf(v.z, v.z, s2); s3 = fmaf(v.w, v.w, s3);
    }
    *dst = (s0 + s1) + (s2 + s3);
    return;
  }
  tid -= BATCH + NTRAIN;

  if (tid < NTRAIN) nb2[tid] = -beta[tid] * 1.4426950408889634f;
}

// ---------------------------------------------------------------------------
// Pass 1: swapped-S 32x32 MFMA. Block = 4 waves x 32 m-rows = 128 m.
// X slab (shared by all 4 waves) staged in LDS via global_load_lds,
// double-buffered; per-wave regs minimized for occupancy.
// ---------------------------------------------------------------------------
// Stage one 32-n slab (XH 4KB + XL 4KB) into lds buffer buf_.
// 8 chunks of 1KB; wave w stages chunks 2w and 2w+1.
#define STAGE(buf_, nbv)                                                      \
  {                                                                           \
    _Pragma("unroll")                                                         \
    for (int q = 0; q < 2; ++q) {                                             \
      const int ch = 2 * w + q;                                               \
      const u16* gsrc = (ch < 4) ? xh : xl;                                   \
      const size_t goff =                                                     \
          ((size_t)((nbv) >> 5) * 4 + (ch & 3)) * 1024 + (size_t)lane * 16;   \
      __builtin_amdgcn_global_load_lds(                                       \
          (const __attribute__((address_space(1))) unsigned int*)(            \
              (const char*)gsrc + goff),                                      \
          (__attribute__((address_space(3))) unsigned int*)&lds[buf_][ch * 1024], \
          16, 0, 0);                                                          \
    }                                                                         \
  }

__global__ __launch_bounds__(256, 3) void grnn_pass1(
    const u16* __restrict__ xh, const u16* __restrict__ xl,
    const u16* __restrict__ yv,
    const float* __restrict__ batches,
    const float* __restrict__ nb2, const float* __restrict__ x2,
    const float* __restrict__ b2,
    float* __restrict__ partial, int chunk_n) {
  __shared__ char lds[2][8192];
  const int w = threadIdx.x >> 6, lane = threadIdx.x & 63;
  const int lr = lane & 31, hi = lane >> 5;
  const int mrow0 = blockIdx.x * 128 + w * 32;  // wave's 32 m-rows
  const int c = blockIdx.y;
  const int n0 = c * chunk_n;
  const int nslab = chunk_n / 32;

  // Batch fragments (B-operand of swapped S): hi/lo, 4 ksteps; b2 scalar.
  short8 AH[4], AL[4];
  const int mrow = mrow0 + lr;
  const float b2v = b2[mrow];
#pragma unroll
  for (int ks = 0; ks < 4; ++ks) {
    const float* src = batches + (size_t)mrow * DIM + ks * 16 + hi * 8;
    float4 v0 = *(const float4*)src;
    float4 v1 = *(const float4*)(src + 4);
    float vv[8] = {v0.x, v0.y, v0.z, v0.w, v1.x, v1.y, v1.z, v1.w};
    short8 hh, ll;
#pragma unroll
    for (int j = 0; j < 8; ++j) {
      u16 hb = f2bf(vv[j]);
      hh[j] = (short)hb;
      ll[j] = (short)f2bf(vv[j] - bf2f(hb));
    }
    AH[ks] = hh;
    AL[ks] = ll;
  }

  f32x16 pv;
#pragma unroll
  for (int r = 0; r < 16; ++r) pv[r] = 0.f;

  const uint4* yv4 = (const uint4*)yv;

  STAGE(0, n0)
  __syncthreads();  // emits s_waitcnt vmcnt(0) lgkmcnt(0) + s_barrier

  for (int s = 0; s < nslab; ++s) {
    const int nb = n0 + s * 32;
    const int cur = s & 1;
    if (s + 1 < nslab) STAGE(cur ^ 1, nb + 32)

    // Per-slab globals (L2-resident; issued early, consumed after MFMAs).
    float4 x2q[4], bq[4];
#pragma unroll
    for (int g = 0; g < 4; ++g) {
      x2q[g] = *(const float4*)&x2[nb + 8 * g + 4 * hi];
      bq[g] = *(const float4*)&nb2[nb + 8 * g + 4 * hi];
    }
    short8 V0 = __builtin_bit_cast(short8, yv4[(size_t)(nb >> 4) * 64 + lane]);
    short8 V1 = __builtin_bit_cast(short8, yv4[(size_t)(nb >> 4) * 64 + 64 + lane]);

    // X fragments from LDS.
    short8 XH[4], XL[4];
#pragma unroll
    for (int ks = 0; ks < 4; ++ks) {
      XH[ks] = __builtin_bit_cast(short8, *(const uint4*)&lds[cur][ks * 1024 + lane * 16]);
      XL[ks] = __builtin_bit_cast(short8, *(const uint4*)&lds[cur][4096 + ks * 1024 + lane * 16]);
    }

    f32x16 sa;
#pragma unroll
    for (int r = 0; r < 16; ++r) sa[r] = 0.f;
    __builtin_amdgcn_s_setprio(1);
#pragma unroll
    for (int ks = 0; ks < 4; ++ks) {
      sa = mfma32(XH[ks], AH[ks], sa);
      sa = mfma32(XL[ks], AH[ks], sa);
      sa = mfma32(XH[ks], AL[ks], sa);
    }
    __builtin_amdgcn_s_setprio(0);

    // w = exp2(nb2 * sqrt(max(b2 + x2 - S, 0))); pack to bf16 in-register.
    unsigned U[8];
#pragma unroll
    for (int p = 0; p < 8; ++p) {
      const int i0 = 2 * p, i1 = 2 * p + 1;
      float t0 = fmaxf(b2v + x2q[i0 >> 2][i0 & 3] - sa[i0], 0.f);
      float t1 = fmaxf(b2v + x2q[i1 >> 2][i1 & 3] - sa[i1], 0.f);
      float w0 = ex2(bq[i0 >> 2][i0 & 3] * __builtin_amdgcn_sqrtf(t0));
      float w1 = ex2(bq[i1 >> 2][i1 & 3] * __builtin_amdgcn_sqrtf(t1));
      U[p] = pkbf(w0, w1);
    }
    plswap(U[0], U[2]); plswap(U[1], U[3]);
    plswap(U[4], U[6]); plswap(U[5], U[7]);
    uint4 a1 = {U[0], U[1], U[2], U[3]};
    uint4 a2 = {U[4], U[5], U[6], U[7]};
    pv = mfma32(__builtin_bit_cast(short8, a1), V0, pv);
    pv = mfma32(__builtin_bit_cast(short8, a2), V1, pv);

    __syncthreads();  // stage for s+1 complete; buffer swap safe
  }

  // Epilogue: col 0 = sum(w), cols 1..8 = sum(w*y).
  float* pc = partial + (size_t)c * 9 * BATCH;
  if (lr < 9) {
#pragma unroll
    for (int r = 0; r < 16; ++r)
      pc[(size_t)lr * BATCH + (mrow0 + (r & 3) + 8 * (r >> 2) + 4 * hi)] = pv[r];
  }
}

// ---------------------------------------------------------------------------
// Pass 2: reduce chunks, divide.
// ---------------------------------------------------------------------------
__global__ __launch_bounds__(256) void grnn_pass2(const float* __restrict__ partial,
                                                  float* __restrict__ out, int nc) {
  int b = blockIdx.x * 256 + threadIdx.x;
  float s1 = 0.f;
  float s2[ODIM];
#pragma unroll
  for (int j = 0; j < ODIM; ++j) s2[j] = 0.f;
  for (int cc = 0; cc < nc; ++cc) {
    const float* p = partial + (size_t)cc * 9 * BATCH;
    s1 += p[b];
#pragma unroll
    for (int j = 0; j < ODIM; ++j) s2[j] += p[(size_t)(j + 1) * BATCH + b];
  }
  const float inv = 1.f / s1;
#pragma unroll
  for (int j = 0; j < ODIM; ++j) out[(size_t)b * ODIM + j] = s2[j] * inv;
}

// ---------------------------------------------------------------------------
extern "C" void kernel_launch(void* const* d_in, const int* in_sizes, int n_in,
                              void* d_out, int out_size, void* d_ws, size_t ws_size,
                              hipStream_t stream) {
  const float* batches = (const float*)d_in[0];  // [8192, 64]
  const float* xt      = (const float*)d_in[1];  // [16384, 64]
  const float* yt      = (const float*)d_in[2];  // [16384, 8]
  const float* beta    = (const float*)d_in[3];  // [1, 16384]
  float* out = (float*)d_out;                    // [8192, 8]

  const size_t xh_b  = (size_t)NTRAIN * DIM * 2;            // 2 MB each
  const size_t yv_b  = (size_t)(NTRAIN / 16) * 64 * 16;     // 1 MB
  const size_t x2_b  = (size_t)NTRAIN * 4;
  const size_t nb2_b = (size_t)NTRAIN * 4;
  const size_t b2_b  = (size_t)BATCH * 4;
  const size_t fixed = 2 * xh_b + yv_b + x2_b + nb2_b + b2_b;
  const size_t per_chunk = (size_t)9 * BATCH * 4;           // 288 KB

  int nc = 32;
  while (nc > 1 && fixed + (size_t)nc * per_chunk > ws_size) nc >>= 1;
  const int chunk_n = NTRAIN / nc;  // multiple of 64 for all nc in {1..32}

  char* p = (char*)d_ws;
  u16* xh = (u16*)p;      p += xh_b;
  u16* xl = (u16*)p;      p += xh_b;
  u16* yv = (u16*)p;      p += yv_b;
  float* x2 = (float*)p;  p += x2_b;
  float* nb2 = (float*)p; p += nb2_b;
  float* b2 = (float*)p;  p += b2_b;
  float* partial = (float*)p;

  const int prep_threads = (NTRAIN / 32) * 4 * 64 + (NTRAIN / 16) * 64 +
                           (BATCH + NTRAIN) + NTRAIN;
  k_prep<<<(prep_threads + 255) / 256, 256, 0, stream>>>(
      batches, xt, yt, beta, xh, xl, yv, b2, x2, nb2);
  grnn_pass1<<<dim3(BATCH / 128, nc), 256, 0, stream>>>(
      xh, xl, yv, batches, nb2, x2, b2, partial, chunk_n);
  grnn_pass2<<<BATCH / 256, 256, 0, stream>>>(partial, out, nc);
}